// Round 24
// baseline (328.168 us; speedup 1.0000x reference)
//
#include <hip/hip_runtime.h>

#define N_NODES 8000
#define FEAT 64
#define HID 128
#define LOOKBACK 12
#define CAP 64

// ---------------- front kernel: zero cnt + weight stacking + init encoder ----------------
__global__ __launch_bounds__(256)
void front_kernel(int* __restrict__ cnt,
                  const float* __restrict__ x,
                  const float* __restrict__ We1, const float* __restrict__ be1,
                  const float* __restrict__ We2, const float* __restrict__ be2,
                  float* __restrict__ out0,
                  const float* __restrict__ Wl1, const float* __restrict__ Wr1,
                  const float* __restrict__ Wl2, const float* __restrict__ Wr2,
                  float* __restrict__ Ws1, float* __restrict__ Wc2) {
    __shared__ float sW1T[HID * LOOKBACK];   // [h][l]
    __shared__ float sB1[HID];
    __shared__ float sW2[HID];
    const int tid = threadIdx.x;
    if (tid < 16) cnt[blockIdx.x * 16 + tid] = 0;
    {   // stack weights: first 2*16384 threads write one elem each
        const int gid = blockIdx.x * 256 + tid;
        if (gid < 128 * 128) {              // Ws1[k][j] = [Wl1;Wr1] row-stacked
            int k = gid >> 7, j = gid & 127;
            Ws1[gid] = (k < 64) ? Wl1[k * 128 + j] : Wr1[(k - 64) * 128 + j];
        } else if (gid < 2 * 128 * 128) {   // Wc2[k][j] = [Wl2 | Wr2] col-stacked
            int w = gid - 128 * 128;
            int k = w >> 7, j = w & 127;
            Wc2[w] = (j < 64) ? Wl2[k * 64 + j] : Wr2[k * 64 + (j - 64)];
        }
    }
    for (int e = tid; e < HID * LOOKBACK; e += 256) {
        int l = e / HID, h = e % HID;
        sW1T[h * LOOKBACK + l] = We1[e];
    }
    for (int e = tid; e < HID; e += 256) { sB1[e] = be1[e]; sW2[e] = We2[e]; }
    __syncthreads();
    int g = (blockIdx.x * 256 + tid) * 4;    // 500*256*4 == N*F exactly
    float xv[4][LOOKBACK];
    #pragma unroll
    for (int l = 0; l < LOOKBACK; ++l) {
        float4 v = *reinterpret_cast<const float4*>(x + (long)l * N_NODES * FEAT + g);
        xv[0][l] = v.x; xv[1][l] = v.y; xv[2][l] = v.z; xv[3][l] = v.w;
    }
    float b2 = be2[0];
    float acc[4] = {b2, b2, b2, b2};
    for (int h = 0; h < HID; ++h) {
        float s0 = sB1[h], s1 = s0, s2 = s0, s3 = s0;
        #pragma unroll
        for (int l = 0; l < LOOKBACK; ++l) {
            float w = sW1T[h * LOOKBACK + l];
            s0 += xv[0][l] * w; s1 += xv[1][l] * w;
            s2 += xv[2][l] * w; s3 += xv[3][l] * w;
        }
        float w2 = sW2[h];
        acc[0] += fmaxf(s0, 0.0f) * w2; acc[1] += fmaxf(s1, 0.0f) * w2;
        acc[2] += fmaxf(s2, 0.0f) * w2; acc[3] += fmaxf(s3, 0.0f) * w2;
    }
    float4 o = {acc[0], acc[1], acc[2], acc[3]};
    *reinterpret_cast<float4*>(out0 + g) = o;
}

// ---------------- adjacency extraction: stream-then-drain (R18/R19-verified, ~47us) ----
__global__ __launch_bounds__(256)
void build_adj_kernel(const float* __restrict__ adj, int* __restrict__ cnt,
                      int* __restrict__ lists) {
    const long NQ = (long)N_NODES * N_NODES / 4;     // 16,000,000 float4s
    const long STRIDE = 2048L * 256;                 // 524,288 threads
    const long t = (long)blockIdx.x * 256 + threadIdx.x;

    int lc = 0;
    int e0 = 0, e1 = 0, e2 = 0, e3 = 0, e4 = 0;
    int e5 = 0, e6 = 0, e7 = 0, e8 = 0, e9 = 0;

    #pragma unroll 1
    for (long q = t; q < NQ; q += STRIDE) {
        float4 w = *reinterpret_cast<const float4*>(adj + 4 * q);
        if (w.x != 0.0f || w.y != 0.0f || w.z != 0.0f || w.w != 0.0f) {
            float wv[4] = {w.x, w.y, w.z, w.w};
            #pragma unroll
            for (int c = 0; c < 4; ++c) {
                if (wv[c] != 0.0f) {
                    int e = (int)(q * 4 + c);        // linear elem idx = i*8000+j
                    if      (lc == 0) e0 = e;
                    else if (lc == 1) e1 = e;
                    else if (lc == 2) e2 = e;
                    else if (lc == 3) e3 = e;
                    else if (lc == 4) e4 = e;
                    else if (lc == 5) e5 = e;
                    else if (lc == 6) e6 = e;
                    else if (lc == 7) e7 = e;
                    else if (lc == 8) e8 = e;
                    else if (lc == 9) e9 = e;
                    ++lc;
                }
            }
        }
    }
    #define DRAIN(K, EK)                                                     \
        if (lc > K) {                                                        \
            int ii = (EK) / N_NODES;                                         \
            int jj = (EK) % N_NODES;                                         \
            int p = atomicAdd(&cnt[jj], 1);                                  \
            if (p < CAP) lists[(long)jj * CAP + p] = ii;                     \
        }
    DRAIN(0, e0) DRAIN(1, e1) DRAIN(2, e2) DRAIN(3, e3) DRAIN(4, e4)
    DRAIN(5, e5) DRAIN(6, e6) DRAIN(7, e7) DRAIN(8, e8) DRAIN(9, e9)
    #undef DRAIN
}

// ---------------- fused SAGE1 + proj + selfMLP (R19 verbatim, +step-0 sort) ----
__global__ __launch_bounds__(256)
void sageproj_kernel(const float* __restrict__ h,
                     int* __restrict__ lists, int* __restrict__ cnt,
                     float* __restrict__ degf, int do_sort,
                     const float* __restrict__ Ws1, const float* __restrict__ bl1,
                     const float* __restrict__ Wc2, const float* __restrict__ bl2,
                     const float* __restrict__ Wf1, const float* __restrict__ bf1,
                     const float* __restrict__ Wf2, const float* __restrict__ bf2,
                     float* __restrict__ pl, float* __restrict__ q) {
    __shared__ float v[16][132];     // [node][k]: k<64 aggr, k>=64 h row
    __shared__ float rr[16][132];    // r1
    __shared__ float tt[16][132];    // t = relu(h@Wf1+bf1)
    __shared__ float xsl[16][68];    // xs
    __shared__ float wbuf[64 * 128]; // 32 KB weight panel chunk
    const int tid = threadIdx.x;
    const int nb = blockIdx.x * 16;
    if (do_sort) {                   // canonicalize own 16 nodes (R16/R19-proven)
        const int wv = tid >> 6, lane = tid & 63;
        #pragma unroll 1
        for (int r = 0; r < 4; ++r) {
            const int n = nb + wv * 4 + r;
            int m = cnt[n]; if (m > CAP) m = CAP;
            int val = (lane < m) ? lists[(long)n * CAP + lane] : 0x7FFFFFFF;
            #pragma unroll
            for (int k = 2; k <= 64; k <<= 1) {
                #pragma unroll
                for (int j = k >> 1; j > 0; j >>= 1) {
                    int other = __shfl_xor(val, j);
                    bool keepMin = (((lane & j) == 0) == ((lane & k) == 0));
                    int mn = val < other ? val : other;
                    int mx = val < other ? other : val;
                    val = keepMin ? mn : mx;
                }
            }
            lists[(long)n * CAP + lane] = val;
            if (lane == 0) { cnt[n] = m; degf[n] = (float)(m > 0 ? m : 1); }
        }
        __syncthreads();
    }
    const int ln = tid >> 4, jg = tid & 15;
    const int n = nb + ln;
    const int c0 = jg * 4;
    {   // gather: 16 threads/node, 4 feats each
        const int m = cnt[n];
        const int* l = lists + (long)n * CAP;
        const float inv = 1.0f / degf[n];
        float4 a = {0, 0, 0, 0};
        for (int e = 0; e < m; ++e) {
            float4 b = *reinterpret_cast<const float4*>(h + (long)l[e] * FEAT + c0);
            a.x += b.x; a.y += b.y; a.z += b.z; a.w += b.w;
        }
        float4 av = {a.x * inv, a.y * inv, a.z * inv, a.w * inv};
        *reinterpret_cast<float4*>(&v[ln][c0]) = av;
        *reinterpret_cast<float4*>(&v[ln][64 + c0]) =
            *reinterpret_cast<const float4*>(h + (long)n * FEAT + c0);
    }
    // ---- P1: rr = relu([aggr|h] @ Ws1 + bl1), K=128 in 2 chunks ----
    {
        float4 b0 = *reinterpret_cast<const float4*>(bl1 + c0);
        float4 b1 = *reinterpret_cast<const float4*>(bl1 + 64 + c0);
        float A0[4] = {b0.x, b0.y, b0.z, b0.w};
        float A1[4] = {b1.x, b1.y, b1.z, b1.w};
        for (int kc = 0; kc < 2; ++kc) {
            __syncthreads();                     // prev consumers done / v ready
            for (int e = tid; e < 2048; e += 256)
                *(reinterpret_cast<float4*>(wbuf) + e) =
                    *(reinterpret_cast<const float4*>(Ws1 + kc * 8192) + e);
            __syncthreads();
            #pragma unroll 4
            for (int k = 0; k < 64; ++k) {
                float a = v[ln][kc * 64 + k];
                float4 w0 = *reinterpret_cast<const float4*>(&wbuf[k * 128 + c0]);
                float4 w1 = *reinterpret_cast<const float4*>(&wbuf[k * 128 + 64 + c0]);
                A0[0] += a * w0.x; A0[1] += a * w0.y; A0[2] += a * w0.z; A0[3] += a * w0.w;
                A1[0] += a * w1.x; A1[1] += a * w1.y; A1[2] += a * w1.z; A1[3] += a * w1.w;
            }
        }
        float4 o0 = {fmaxf(A0[0],0.f), fmaxf(A0[1],0.f), fmaxf(A0[2],0.f), fmaxf(A0[3],0.f)};
        float4 o1 = {fmaxf(A1[0],0.f), fmaxf(A1[1],0.f), fmaxf(A1[2],0.f), fmaxf(A1[3],0.f)};
        *reinterpret_cast<float4*>(&rr[ln][c0]) = o0;
        *reinterpret_cast<float4*>(&rr[ln][64 + c0]) = o1;
    }
    // ---- P2: tt = relu(h @ Wf1 + bf1), K=64, one chunk ----
    {
        float4 b0 = *reinterpret_cast<const float4*>(bf1 + c0);
        float4 b1 = *reinterpret_cast<const float4*>(bf1 + 64 + c0);
        float A0[4] = {b0.x, b0.y, b0.z, b0.w};
        float A1[4] = {b1.x, b1.y, b1.z, b1.w};
        __syncthreads();
        for (int e = tid; e < 2048; e += 256)
            *(reinterpret_cast<float4*>(wbuf) + e) =
                *(reinterpret_cast<const float4*>(Wf1) + e);
        __syncthreads();
        #pragma unroll 4
        for (int k = 0; k < 64; ++k) {
            float a = v[ln][64 + k];
            float4 w0 = *reinterpret_cast<const float4*>(&wbuf[k * 128 + c0]);
            float4 w1 = *reinterpret_cast<const float4*>(&wbuf[k * 128 + 64 + c0]);
            A0[0] += a * w0.x; A0[1] += a * w0.y; A0[2] += a * w0.z; A0[3] += a * w0.w;
            A1[0] += a * w1.x; A1[1] += a * w1.y; A1[2] += a * w1.z; A1[3] += a * w1.w;
        }
        float4 o0 = {fmaxf(A0[0],0.f), fmaxf(A0[1],0.f), fmaxf(A0[2],0.f), fmaxf(A0[3],0.f)};
        float4 o1 = {fmaxf(A1[0],0.f), fmaxf(A1[1],0.f), fmaxf(A1[2],0.f), fmaxf(A1[3],0.f)};
        *reinterpret_cast<float4*>(&tt[ln][c0]) = o0;
        *reinterpret_cast<float4*>(&tt[ln][64 + c0]) = o1;
    }
    // ---- P3: xsl = tt @ Wf2 + bf2, K=128, 64 cols (Wf2 = [128][64]) ----
    {
        float4 b0 = *reinterpret_cast<const float4*>(bf2 + c0);
        float X[4] = {b0.x, b0.y, b0.z, b0.w};
        __syncthreads();
        for (int e = tid; e < 2048; e += 256)
            *(reinterpret_cast<float4*>(wbuf) + e) =
                *(reinterpret_cast<const float4*>(Wf2) + e);
        __syncthreads();
        #pragma unroll 4
        for (int k = 0; k < 128; ++k) {
            float a = tt[ln][k];
            float4 w = *reinterpret_cast<const float4*>(&wbuf[k * 64 + c0]);
            X[0] += a * w.x; X[1] += a * w.y; X[2] += a * w.z; X[3] += a * w.w;
        }
        float4 o = {X[0], X[1], X[2], X[3]};
        *reinterpret_cast<float4*>(&xsl[ln][c0]) = o;
    }
    // ---- P4: [pl|q] = rr @ Wc2 (+ bl2 + xsl on q half), K=128 in 2 chunks ----
    {
        float P0[4] = {0, 0, 0, 0};
        float P1[4] = {0, 0, 0, 0};
        for (int kc = 0; kc < 2; ++kc) {
            __syncthreads();
            for (int e = tid; e < 2048; e += 256)
                *(reinterpret_cast<float4*>(wbuf) + e) =
                    *(reinterpret_cast<const float4*>(Wc2 + kc * 8192) + e);
            __syncthreads();
            #pragma unroll 4
            for (int k = 0; k < 64; ++k) {
                float a = rr[ln][kc * 64 + k];
                float4 w0 = *reinterpret_cast<const float4*>(&wbuf[k * 128 + c0]);
                float4 w1 = *reinterpret_cast<const float4*>(&wbuf[k * 128 + 64 + c0]);
                P0[0] += a * w0.x; P0[1] += a * w0.y; P0[2] += a * w0.z; P0[3] += a * w0.w;
                P1[0] += a * w1.x; P1[1] += a * w1.y; P1[2] += a * w1.z; P1[3] += a * w1.w;
            }
        }
        float4 op = {P0[0], P0[1], P0[2], P0[3]};
        *reinterpret_cast<float4*>(pl + (long)n * FEAT + c0) = op;
        float4 bv = *reinterpret_cast<const float4*>(bl2 + c0);
        float4 oq = {P1[0] + bv.x + xsl[ln][c0 + 0],
                     P1[1] + bv.y + xsl[ln][c0 + 1],
                     P1[2] + bv.z + xsl[ln][c0 + 2],
                     P1[3] + bv.w + xsl[ln][c0 + 3]};
        *reinterpret_cast<float4*>(q + (long)n * FEAT + c0) = oq;
    }
}

// ---------------- gather + Euler epilogue (R12 verbatim) ----------------
__global__ __launch_bounds__(256)
void epi_kernel(const float* __restrict__ pl, const float* __restrict__ q,
                const int* __restrict__ lists, const int* __restrict__ cnt,
                const float* __restrict__ degf, const float* __restrict__ hcur,
                const float* __restrict__ tspan, int step,
                float* __restrict__ hnext) {
    const int tid = threadIdx.x;
    const int ln = tid >> 4, sub = tid & 15;
    const int n = blockIdx.x * 16 + ln;
    const int f0 = sub * 4;
    const int m = cnt[n];
    const int* l = lists + (long)n * CAP;
    const float inv = 1.0f / degf[n];
    float4 a = {0, 0, 0, 0};
    for (int e = 0; e < m; ++e) {
        float4 b = *reinterpret_cast<const float4*>(pl + (long)l[e] * FEAT + f0);
        a.x += b.x; a.y += b.y; a.z += b.z; a.w += b.w;
    }
    const float dt = tspan[step + 1] - tspan[step];
    float4 qv = *reinterpret_cast<const float4*>(q + (long)n * FEAT + f0);
    float4 hv = *reinterpret_cast<const float4*>(hcur + (long)n * FEAT + f0);
    float s0 = qv.x + a.x * inv, s1 = qv.y + a.y * inv;
    float s2 = qv.z + a.z * inv, s3 = qv.w + a.w * inv;
    s0 = fminf(fmaxf(s0, -1000.f), 1000.f); s1 = fminf(fmaxf(s1, -1000.f), 1000.f);
    s2 = fminf(fmaxf(s2, -1000.f), 1000.f); s3 = fminf(fmaxf(s3, -1000.f), 1000.f);
    float4 o = {hv.x + dt * s0, hv.y + dt * s1, hv.z + dt * s2, hv.w + dt * s3};
    *reinterpret_cast<float4*>(hnext + (long)n * FEAT + f0) = o;
}

extern "C" void kernel_launch(void* const* d_in, const int* in_sizes, int n_in,
                              void* d_out, int out_size, void* d_ws, size_t ws_size,
                              hipStream_t stream) {
    const float* tspan = (const float*)d_in[0];
    const float* x     = (const float*)d_in[1];
    const float* adj   = (const float*)d_in[2];
    const float* We1   = (const float*)d_in[3];
    const float* be1   = (const float*)d_in[4];
    const float* We2   = (const float*)d_in[5];
    const float* be2   = (const float*)d_in[6];
    const float* Wf1   = (const float*)d_in[7];
    const float* bf1   = (const float*)d_in[8];
    const float* Wf2   = (const float*)d_in[9];
    const float* bf2   = (const float*)d_in[10];
    const float* Wl1   = (const float*)d_in[11];
    const float* bl1   = (const float*)d_in[12];
    const float* Wr1   = (const float*)d_in[13];
    const float* Wl2   = (const float*)d_in[14];
    const float* bl2   = (const float*)d_in[15];
    const float* Wr2   = (const float*)d_in[16];
    float* out = (float*)d_out;

    // workspace layout (bytes)
    char* ws = (char*)d_ws;
    int*   lists = (int*)  (ws + 0);           // 8000*64*4  = 2,048,000
    int*   cnt   = (int*)  (ws + 2048000);     // 32,000
    float* degf  = (float*)(ws + 2080000);     // 32,000
    float* Ws1   = (float*)(ws + 2112000);     // 65,536
    float* Wc2   = (float*)(ws + 2177536);     // 65,536
    float* pl    = (float*)(ws + 2243072);     // 2,048,000
    float* q     = (float*)(ws + 4291072);     // 2,048,000
    float* pl2   = (float*)(ws + 6339072);     // 2,048,000 (probe scratch)
    float* q2    = (float*)(ws + 8387072);     // 2,048,000 (probe scratch)
    // total 10,435,072 bytes

    front_kernel<<<500, 256, 0, stream>>>(cnt, x, We1, be1, We2, be2, out,
                                          Wl1, Wr1, Wl2, Wr2, Ws1, Wc2);
    build_adj_kernel<<<2048, 256, 0, stream>>>(adj, cnt, lists);

    for (int s = 0; s < 3; ++s) {
        const float* hcur  = out + (long)s       * N_NODES * FEAT;
        float*       hnext = out + (long)(s + 1) * N_NODES * FEAT;
        sageproj_kernel<<<500, 256, 0, stream>>>(hcur, lists, cnt, degf, (s == 0) ? 1 : 0,
                                                 Ws1, bl1, Wc2, bl2,
                                                 Wf1, bf1, Wf2, bf2, pl, q);
        epi_kernel<<<500, 256, 0, stream>>>(pl, q, lists, cnt, degf, hcur, tspan, s, hnext);
    }

    // ---- 3x sage PROBES (measurement only; scratch outputs, final-h input) ----
    const float* hfin = out + 3L * N_NODES * FEAT;
    for (int p = 0; p < 3; ++p) {
        sageproj_kernel<<<500, 256, 0, stream>>>(hfin, lists, cnt, degf, 0,
                                                 Ws1, bl1, Wc2, bl2,
                                                 Wf1, bf1, Wf2, bf2, pl2, q2);
    }
}

// Round 25
// 218.420 us; speedup vs baseline: 1.5025x; 1.5025x over previous
//
#include <hip/hip_runtime.h>

#define N_NODES 8000
#define FEAT 64
#define HID 128
#define LOOKBACK 12
#define CAP 64

// ---------------- front kernel: zero cnt + weight stacking + init encoder ----------------
__global__ __launch_bounds__(256)
void front_kernel(int* __restrict__ cnt,
                  const float* __restrict__ x,
                  const float* __restrict__ We1, const float* __restrict__ be1,
                  const float* __restrict__ We2, const float* __restrict__ be2,
                  float* __restrict__ out0,
                  const float* __restrict__ Wl1, const float* __restrict__ Wr1,
                  const float* __restrict__ Wl2, const float* __restrict__ Wr2,
                  float* __restrict__ Ws1, float* __restrict__ Wc2) {
    __shared__ float sW1T[HID * LOOKBACK];   // [h][l]
    __shared__ float sB1[HID];
    __shared__ float sW2[HID];
    const int tid = threadIdx.x;
    if (tid < 16) cnt[blockIdx.x * 16 + tid] = 0;
    {   // stack weights: first 2*16384 threads write one elem each
        const int gid = blockIdx.x * 256 + tid;
        if (gid < 128 * 128) {              // Ws1[k][j] = [Wl1;Wr1] row-stacked
            int k = gid >> 7, j = gid & 127;
            Ws1[gid] = (k < 64) ? Wl1[k * 128 + j] : Wr1[(k - 64) * 128 + j];
        } else if (gid < 2 * 128 * 128) {   // Wc2[k][j] = [Wl2 | Wr2] col-stacked
            int w = gid - 128 * 128;
            int k = w >> 7, j = w & 127;
            Wc2[w] = (j < 64) ? Wl2[k * 64 + j] : Wr2[k * 64 + (j - 64)];
        }
    }
    for (int e = tid; e < HID * LOOKBACK; e += 256) {
        int l = e / HID, h = e % HID;
        sW1T[h * LOOKBACK + l] = We1[e];
    }
    for (int e = tid; e < HID; e += 256) { sB1[e] = be1[e]; sW2[e] = We2[e]; }
    __syncthreads();
    int g = (blockIdx.x * 256 + tid) * 4;    // 500*256*4 == N*F exactly
    float xv[4][LOOKBACK];
    #pragma unroll
    for (int l = 0; l < LOOKBACK; ++l) {
        float4 v = *reinterpret_cast<const float4*>(x + (long)l * N_NODES * FEAT + g);
        xv[0][l] = v.x; xv[1][l] = v.y; xv[2][l] = v.z; xv[3][l] = v.w;
    }
    float b2 = be2[0];
    float acc[4] = {b2, b2, b2, b2};
    for (int h = 0; h < HID; ++h) {
        float s0 = sB1[h], s1 = s0, s2 = s0, s3 = s0;
        #pragma unroll
        for (int l = 0; l < LOOKBACK; ++l) {
            float w = sW1T[h * LOOKBACK + l];
            s0 += xv[0][l] * w; s1 += xv[1][l] * w;
            s2 += xv[2][l] * w; s3 += xv[3][l] * w;
        }
        float w2 = sW2[h];
        acc[0] += fmaxf(s0, 0.0f) * w2; acc[1] += fmaxf(s1, 0.0f) * w2;
        acc[2] += fmaxf(s2, 0.0f) * w2; acc[3] += fmaxf(s3, 0.0f) * w2;
    }
    float4 o = {acc[0], acc[1], acc[2], acc[3]};
    *reinterpret_cast<float4*>(out0 + g) = o;
}

// ---------------- adjacency extraction: stream-then-drain (R18/R19-verified, ~47us) ----
__global__ __launch_bounds__(256)
void build_adj_kernel(const float* __restrict__ adj, int* __restrict__ cnt,
                      int* __restrict__ lists) {
    const long NQ = (long)N_NODES * N_NODES / 4;     // 16,000,000 float4s
    const long STRIDE = 2048L * 256;                 // 524,288 threads
    const long t = (long)blockIdx.x * 256 + threadIdx.x;

    int lc = 0;
    int e0 = 0, e1 = 0, e2 = 0, e3 = 0, e4 = 0;
    int e5 = 0, e6 = 0, e7 = 0, e8 = 0, e9 = 0;

    #pragma unroll 1
    for (long q = t; q < NQ; q += STRIDE) {
        float4 w = *reinterpret_cast<const float4*>(adj + 4 * q);
        if (w.x != 0.0f || w.y != 0.0f || w.z != 0.0f || w.w != 0.0f) {
            float wv[4] = {w.x, w.y, w.z, w.w};
            #pragma unroll
            for (int c = 0; c < 4; ++c) {
                if (wv[c] != 0.0f) {
                    int e = (int)(q * 4 + c);        // linear elem idx = i*8000+j
                    if      (lc == 0) e0 = e;
                    else if (lc == 1) e1 = e;
                    else if (lc == 2) e2 = e;
                    else if (lc == 3) e3 = e;
                    else if (lc == 4) e4 = e;
                    else if (lc == 5) e5 = e;
                    else if (lc == 6) e6 = e;
                    else if (lc == 7) e7 = e;
                    else if (lc == 8) e8 = e;
                    else if (lc == 9) e9 = e;
                    ++lc;
                }
            }
        }
    }
    #define DRAIN(K, EK)                                                     \
        if (lc > K) {                                                        \
            int ii = (EK) / N_NODES;                                         \
            int jj = (EK) % N_NODES;                                         \
            int p = atomicAdd(&cnt[jj], 1);                                  \
            if (p < CAP) lists[(long)jj * CAP + p] = ii;                     \
        }
    DRAIN(0, e0) DRAIN(1, e1) DRAIN(2, e2) DRAIN(3, e3) DRAIN(4, e4)
    DRAIN(5, e5) DRAIN(6, e6) DRAIN(7, e7) DRAIN(8, e8) DRAIN(9, e9)
    #undef DRAIN
}

// ---------------- fused SAGE1 + proj + selfMLP (R19 verbatim, +step-0 sort) ----
__global__ __launch_bounds__(256)
void sageproj_kernel(const float* __restrict__ h,
                     int* __restrict__ lists, int* __restrict__ cnt,
                     float* __restrict__ degf, int do_sort,
                     const float* __restrict__ Ws1, const float* __restrict__ bl1,
                     const float* __restrict__ Wc2, const float* __restrict__ bl2,
                     const float* __restrict__ Wf1, const float* __restrict__ bf1,
                     const float* __restrict__ Wf2, const float* __restrict__ bf2,
                     float* __restrict__ pl, float* __restrict__ q) {
    __shared__ float v[16][132];     // [node][k]: k<64 aggr, k>=64 h row
    __shared__ float rr[16][132];    // r1
    __shared__ float tt[16][132];    // t = relu(h@Wf1+bf1)
    __shared__ float xsl[16][68];    // xs
    __shared__ float wbuf[64 * 128]; // 32 KB weight panel chunk
    const int tid = threadIdx.x;
    const int nb = blockIdx.x * 16;
    if (do_sort) {                   // canonicalize own 16 nodes (R16/R19-proven)
        const int wv = tid >> 6, lane = tid & 63;
        #pragma unroll 1
        for (int r = 0; r < 4; ++r) {
            const int n = nb + wv * 4 + r;
            int m = cnt[n]; if (m > CAP) m = CAP;
            int val = (lane < m) ? lists[(long)n * CAP + lane] : 0x7FFFFFFF;
            #pragma unroll
            for (int k = 2; k <= 64; k <<= 1) {
                #pragma unroll
                for (int j = k >> 1; j > 0; j >>= 1) {
                    int other = __shfl_xor(val, j);
                    bool keepMin = (((lane & j) == 0) == ((lane & k) == 0));
                    int mn = val < other ? val : other;
                    int mx = val < other ? other : val;
                    val = keepMin ? mn : mx;
                }
            }
            lists[(long)n * CAP + lane] = val;
            if (lane == 0) { cnt[n] = m; degf[n] = (float)(m > 0 ? m : 1); }
        }
        __syncthreads();
    }
    const int ln = tid >> 4, jg = tid & 15;
    const int n = nb + ln;
    const int c0 = jg * 4;
    {   // gather: 16 threads/node, 4 feats each
        const int m = cnt[n];
        const int* l = lists + (long)n * CAP;
        const float inv = 1.0f / degf[n];
        float4 a = {0, 0, 0, 0};
        for (int e = 0; e < m; ++e) {
            float4 b = *reinterpret_cast<const float4*>(h + (long)l[e] * FEAT + c0);
            a.x += b.x; a.y += b.y; a.z += b.z; a.w += b.w;
        }
        float4 av = {a.x * inv, a.y * inv, a.z * inv, a.w * inv};
        *reinterpret_cast<float4*>(&v[ln][c0]) = av;
        *reinterpret_cast<float4*>(&v[ln][64 + c0]) =
            *reinterpret_cast<const float4*>(h + (long)n * FEAT + c0);
    }
    // ---- P1: rr = relu([aggr|h] @ Ws1 + bl1), K=128 in 2 chunks ----
    {
        float4 b0 = *reinterpret_cast<const float4*>(bl1 + c0);
        float4 b1 = *reinterpret_cast<const float4*>(bl1 + 64 + c0);
        float A0[4] = {b0.x, b0.y, b0.z, b0.w};
        float A1[4] = {b1.x, b1.y, b1.z, b1.w};
        for (int kc = 0; kc < 2; ++kc) {
            __syncthreads();                     // prev consumers done / v ready
            for (int e = tid; e < 2048; e += 256)
                *(reinterpret_cast<float4*>(wbuf) + e) =
                    *(reinterpret_cast<const float4*>(Ws1 + kc * 8192) + e);
            __syncthreads();
            #pragma unroll 4
            for (int k = 0; k < 64; ++k) {
                float a = v[ln][kc * 64 + k];
                float4 w0 = *reinterpret_cast<const float4*>(&wbuf[k * 128 + c0]);
                float4 w1 = *reinterpret_cast<const float4*>(&wbuf[k * 128 + 64 + c0]);
                A0[0] += a * w0.x; A0[1] += a * w0.y; A0[2] += a * w0.z; A0[3] += a * w0.w;
                A1[0] += a * w1.x; A1[1] += a * w1.y; A1[2] += a * w1.z; A1[3] += a * w1.w;
            }
        }
        float4 o0 = {fmaxf(A0[0],0.f), fmaxf(A0[1],0.f), fmaxf(A0[2],0.f), fmaxf(A0[3],0.f)};
        float4 o1 = {fmaxf(A1[0],0.f), fmaxf(A1[1],0.f), fmaxf(A1[2],0.f), fmaxf(A1[3],0.f)};
        *reinterpret_cast<float4*>(&rr[ln][c0]) = o0;
        *reinterpret_cast<float4*>(&rr[ln][64 + c0]) = o1;
    }
    // ---- P2: tt = relu(h @ Wf1 + bf1), K=64, one chunk ----
    {
        float4 b0 = *reinterpret_cast<const float4*>(bf1 + c0);
        float4 b1 = *reinterpret_cast<const float4*>(bf1 + 64 + c0);
        float A0[4] = {b0.x, b0.y, b0.z, b0.w};
        float A1[4] = {b1.x, b1.y, b1.z, b1.w};
        __syncthreads();
        for (int e = tid; e < 2048; e += 256)
            *(reinterpret_cast<float4*>(wbuf) + e) =
                *(reinterpret_cast<const float4*>(Wf1) + e);
        __syncthreads();
        #pragma unroll 4
        for (int k = 0; k < 64; ++k) {
            float a = v[ln][64 + k];
            float4 w0 = *reinterpret_cast<const float4*>(&wbuf[k * 128 + c0]);
            float4 w1 = *reinterpret_cast<const float4*>(&wbuf[k * 128 + 64 + c0]);
            A0[0] += a * w0.x; A0[1] += a * w0.y; A0[2] += a * w0.z; A0[3] += a * w0.w;
            A1[0] += a * w1.x; A1[1] += a * w1.y; A1[2] += a * w1.z; A1[3] += a * w1.w;
        }
        float4 o0 = {fmaxf(A0[0],0.f), fmaxf(A0[1],0.f), fmaxf(A0[2],0.f), fmaxf(A0[3],0.f)};
        float4 o1 = {fmaxf(A1[0],0.f), fmaxf(A1[1],0.f), fmaxf(A1[2],0.f), fmaxf(A1[3],0.f)};
        *reinterpret_cast<float4*>(&tt[ln][c0]) = o0;
        *reinterpret_cast<float4*>(&tt[ln][64 + c0]) = o1;
    }
    // ---- P3: xsl = tt @ Wf2 + bf2, K=128, 64 cols (Wf2 = [128][64]) ----
    {
        float4 b0 = *reinterpret_cast<const float4*>(bf2 + c0);
        float X[4] = {b0.x, b0.y, b0.z, b0.w};
        __syncthreads();
        for (int e = tid; e < 2048; e += 256)
            *(reinterpret_cast<float4*>(wbuf) + e) =
                *(reinterpret_cast<const float4*>(Wf2) + e);
        __syncthreads();
        #pragma unroll 4
        for (int k = 0; k < 128; ++k) {
            float a = tt[ln][k];
            float4 w = *reinterpret_cast<const float4*>(&wbuf[k * 64 + c0]);
            X[0] += a * w.x; X[1] += a * w.y; X[2] += a * w.z; X[3] += a * w.w;
        }
        float4 o = {X[0], X[1], X[2], X[3]};
        *reinterpret_cast<float4*>(&xsl[ln][c0]) = o;
    }
    // ---- P4: [pl|q] = rr @ Wc2 (+ bl2 + xsl on q half), K=128 in 2 chunks ----
    {
        float P0[4] = {0, 0, 0, 0};
        float P1[4] = {0, 0, 0, 0};
        for (int kc = 0; kc < 2; ++kc) {
            __syncthreads();
            for (int e = tid; e < 2048; e += 256)
                *(reinterpret_cast<float4*>(wbuf) + e) =
                    *(reinterpret_cast<const float4*>(Wc2 + kc * 8192) + e);
            __syncthreads();
            #pragma unroll 4
            for (int k = 0; k < 64; ++k) {
                float a = rr[ln][kc * 64 + k];
                float4 w0 = *reinterpret_cast<const float4*>(&wbuf[k * 128 + c0]);
                float4 w1 = *reinterpret_cast<const float4*>(&wbuf[k * 128 + 64 + c0]);
                P0[0] += a * w0.x; P0[1] += a * w0.y; P0[2] += a * w0.z; P0[3] += a * w0.w;
                P1[0] += a * w1.x; P1[1] += a * w1.y; P1[2] += a * w1.z; P1[3] += a * w1.w;
            }
        }
        float4 op = {P0[0], P0[1], P0[2], P0[3]};
        *reinterpret_cast<float4*>(pl + (long)n * FEAT + c0) = op;
        float4 bv = *reinterpret_cast<const float4*>(bl2 + c0);
        float4 oq = {P1[0] + bv.x + xsl[ln][c0 + 0],
                     P1[1] + bv.y + xsl[ln][c0 + 1],
                     P1[2] + bv.z + xsl[ln][c0 + 2],
                     P1[3] + bv.w + xsl[ln][c0 + 3]};
        *reinterpret_cast<float4*>(q + (long)n * FEAT + c0) = oq;
    }
}

// ---------------- gather + Euler epilogue v2: 64 threads/node ----------------
// R24 probe: epi ~29us/step, dominated by the serial 16-deep dependent gather
// chain at only ~8 waves/CU. v2: 4 neighbor-groups x 16 f-threads per node
// (chain 16->4), wave-local shfl_xor reduction; 2000 blocks -> 4x TLP.
// Summation order changes (deterministic: sorted lists, fixed tree).
__global__ __launch_bounds__(256)
void epi_kernel(const float* __restrict__ pl, const float* __restrict__ q,
                const int* __restrict__ lists, const int* __restrict__ cnt,
                const float* __restrict__ degf, const float* __restrict__ hcur,
                const float* __restrict__ tspan, int step,
                float* __restrict__ hnext) {
    const int tid  = threadIdx.x;
    const int nw   = tid >> 6;            // node within block (one wave per node)
    const int lane = tid & 63;
    const int n  = blockIdx.x * 4 + nw;
    const int f0 = (lane & 15) * 4;
    const int eg = lane >> 4;             // neighbor group 0..3
    const int m  = cnt[n];
    const int* l = lists + (long)n * CAP;
    float4 a = {0, 0, 0, 0};
    for (int e = eg; e < m; e += 4) {
        float4 b = *reinterpret_cast<const float4*>(pl + (long)l[e] * FEAT + f0);
        a.x += b.x; a.y += b.y; a.z += b.z; a.w += b.w;
    }
    // reduce the 4 neighbor-group partials (lanes differing in bits 4,5)
    a.x += __shfl_xor(a.x, 16); a.y += __shfl_xor(a.y, 16);
    a.z += __shfl_xor(a.z, 16); a.w += __shfl_xor(a.w, 16);
    a.x += __shfl_xor(a.x, 32); a.y += __shfl_xor(a.y, 32);
    a.z += __shfl_xor(a.z, 32); a.w += __shfl_xor(a.w, 32);
    if (eg == 0) {
        const float inv = 1.0f / degf[n];
        const float dt = tspan[step + 1] - tspan[step];
        float4 qv = *reinterpret_cast<const float4*>(q + (long)n * FEAT + f0);
        float4 hv = *reinterpret_cast<const float4*>(hcur + (long)n * FEAT + f0);
        float s0 = qv.x + a.x * inv, s1 = qv.y + a.y * inv;
        float s2 = qv.z + a.z * inv, s3 = qv.w + a.w * inv;
        s0 = fminf(fmaxf(s0, -1000.f), 1000.f); s1 = fminf(fmaxf(s1, -1000.f), 1000.f);
        s2 = fminf(fmaxf(s2, -1000.f), 1000.f); s3 = fminf(fmaxf(s3, -1000.f), 1000.f);
        float4 o = {hv.x + dt * s0, hv.y + dt * s1, hv.z + dt * s2, hv.w + dt * s3};
        *reinterpret_cast<float4*>(hnext + (long)n * FEAT + f0) = o;
    }
}

extern "C" void kernel_launch(void* const* d_in, const int* in_sizes, int n_in,
                              void* d_out, int out_size, void* d_ws, size_t ws_size,
                              hipStream_t stream) {
    const float* tspan = (const float*)d_in[0];
    const float* x     = (const float*)d_in[1];
    const float* adj   = (const float*)d_in[2];
    const float* We1   = (const float*)d_in[3];
    const float* be1   = (const float*)d_in[4];
    const float* We2   = (const float*)d_in[5];
    const float* be2   = (const float*)d_in[6];
    const float* Wf1   = (const float*)d_in[7];
    const float* bf1   = (const float*)d_in[8];
    const float* Wf2   = (const float*)d_in[9];
    const float* bf2   = (const float*)d_in[10];
    const float* Wl1   = (const float*)d_in[11];
    const float* bl1   = (const float*)d_in[12];
    const float* Wr1   = (const float*)d_in[13];
    const float* Wl2   = (const float*)d_in[14];
    const float* bl2   = (const float*)d_in[15];
    const float* Wr2   = (const float*)d_in[16];
    float* out = (float*)d_out;

    // workspace layout (bytes)
    char* ws = (char*)d_ws;
    int*   lists = (int*)  (ws + 0);           // 8000*64*4  = 2,048,000
    int*   cnt   = (int*)  (ws + 2048000);     // 32,000
    float* degf  = (float*)(ws + 2080000);     // 32,000
    float* Ws1   = (float*)(ws + 2112000);     // 65,536
    float* Wc2   = (float*)(ws + 2177536);     // 65,536
    float* pl    = (float*)(ws + 2243072);     // 2,048,000
    float* q     = (float*)(ws + 4291072);     // 2,048,000
    // total 6,339,072 bytes

    front_kernel<<<500, 256, 0, stream>>>(cnt, x, We1, be1, We2, be2, out,
                                          Wl1, Wr1, Wl2, Wr2, Ws1, Wc2);
    build_adj_kernel<<<2048, 256, 0, stream>>>(adj, cnt, lists);

    for (int s = 0; s < 3; ++s) {
        const float* hcur  = out + (long)s       * N_NODES * FEAT;
        float*       hnext = out + (long)(s + 1) * N_NODES * FEAT;
        sageproj_kernel<<<500, 256, 0, stream>>>(hcur, lists, cnt, degf, (s == 0) ? 1 : 0,
                                                 Ws1, bl1, Wc2, bl2,
                                                 Wf1, bf1, Wf2, bf2, pl, q);
        epi_kernel<<<2000, 256, 0, stream>>>(pl, q, lists, cnt, degf, hcur, tspan, s, hnext);
    }
}

// Round 26
// 205.192 us; speedup vs baseline: 1.5993x; 1.0645x over previous
//
#include <hip/hip_runtime.h>

#define N_NODES 8000
#define FEAT 64
#define HID 128
#define LOOKBACK 12
#define CAP 64

// ---------------- front kernel: zero cnt + weight stacking + init encoder ----------------
__global__ __launch_bounds__(256)
void front_kernel(int* __restrict__ cnt,
                  const float* __restrict__ x,
                  const float* __restrict__ We1, const float* __restrict__ be1,
                  const float* __restrict__ We2, const float* __restrict__ be2,
                  float* __restrict__ out0,
                  const float* __restrict__ Wl1, const float* __restrict__ Wr1,
                  const float* __restrict__ Wl2, const float* __restrict__ Wr2,
                  float* __restrict__ Ws1, float* __restrict__ Wc2) {
    __shared__ float sW1T[HID * LOOKBACK];   // [h][l]
    __shared__ float sB1[HID];
    __shared__ float sW2[HID];
    const int tid = threadIdx.x;
    if (tid < 16) cnt[blockIdx.x * 16 + tid] = 0;
    {   // stack weights: first 2*16384 threads write one elem each
        const int gid = blockIdx.x * 256 + tid;
        if (gid < 128 * 128) {              // Ws1[k][j] = [Wl1;Wr1] row-stacked
            int k = gid >> 7, j = gid & 127;
            Ws1[gid] = (k < 64) ? Wl1[k * 128 + j] : Wr1[(k - 64) * 128 + j];
        } else if (gid < 2 * 128 * 128) {   // Wc2[k][j] = [Wl2 | Wr2] col-stacked
            int w = gid - 128 * 128;
            int k = w >> 7, j = w & 127;
            Wc2[w] = (j < 64) ? Wl2[k * 64 + j] : Wr2[k * 64 + (j - 64)];
        }
    }
    for (int e = tid; e < HID * LOOKBACK; e += 256) {
        int l = e / HID, h = e % HID;
        sW1T[h * LOOKBACK + l] = We1[e];
    }
    for (int e = tid; e < HID; e += 256) { sB1[e] = be1[e]; sW2[e] = We2[e]; }
    __syncthreads();
    int g = (blockIdx.x * 256 + tid) * 4;    // 500*256*4 == N*F exactly
    float xv[4][LOOKBACK];
    #pragma unroll
    for (int l = 0; l < LOOKBACK; ++l) {
        float4 v = *reinterpret_cast<const float4*>(x + (long)l * N_NODES * FEAT + g);
        xv[0][l] = v.x; xv[1][l] = v.y; xv[2][l] = v.z; xv[3][l] = v.w;
    }
    float b2 = be2[0];
    float acc[4] = {b2, b2, b2, b2};
    for (int h = 0; h < HID; ++h) {
        float s0 = sB1[h], s1 = s0, s2 = s0, s3 = s0;
        #pragma unroll
        for (int l = 0; l < LOOKBACK; ++l) {
            float w = sW1T[h * LOOKBACK + l];
            s0 += xv[0][l] * w; s1 += xv[1][l] * w;
            s2 += xv[2][l] * w; s3 += xv[3][l] * w;
        }
        float w2 = sW2[h];
        acc[0] += fmaxf(s0, 0.0f) * w2; acc[1] += fmaxf(s1, 0.0f) * w2;
        acc[2] += fmaxf(s2, 0.0f) * w2; acc[3] += fmaxf(s3, 0.0f) * w2;
    }
    float4 o = {acc[0], acc[1], acc[2], acc[3]};
    *reinterpret_cast<float4*>(out0 + g) = o;
}

// ---------------- adjacency extraction: stream-then-drain (R18/R19-verified, ~47us) ----
__global__ __launch_bounds__(256)
void build_adj_kernel(const float* __restrict__ adj, int* __restrict__ cnt,
                      int* __restrict__ lists) {
    const long NQ = (long)N_NODES * N_NODES / 4;     // 16,000,000 float4s
    const long STRIDE = 2048L * 256;                 // 524,288 threads
    const long t = (long)blockIdx.x * 256 + threadIdx.x;

    int lc = 0;
    int e0 = 0, e1 = 0, e2 = 0, e3 = 0, e4 = 0;
    int e5 = 0, e6 = 0, e7 = 0, e8 = 0, e9 = 0;

    #pragma unroll 1
    for (long q = t; q < NQ; q += STRIDE) {
        float4 w = *reinterpret_cast<const float4*>(adj + 4 * q);
        if (w.x != 0.0f || w.y != 0.0f || w.z != 0.0f || w.w != 0.0f) {
            float wv[4] = {w.x, w.y, w.z, w.w};
            #pragma unroll
            for (int c = 0; c < 4; ++c) {
                if (wv[c] != 0.0f) {
                    int e = (int)(q * 4 + c);        // linear elem idx = i*8000+j
                    if      (lc == 0) e0 = e;
                    else if (lc == 1) e1 = e;
                    else if (lc == 2) e2 = e;
                    else if (lc == 3) e3 = e;
                    else if (lc == 4) e4 = e;
                    else if (lc == 5) e5 = e;
                    else if (lc == 6) e6 = e;
                    else if (lc == 7) e7 = e;
                    else if (lc == 8) e8 = e;
                    else if (lc == 9) e9 = e;
                    ++lc;
                }
            }
        }
    }
    #define DRAIN(K, EK)                                                     \
        if (lc > K) {                                                        \
            int ii = (EK) / N_NODES;                                         \
            int jj = (EK) % N_NODES;                                         \
            int p = atomicAdd(&cnt[jj], 1);                                  \
            if (p < CAP) lists[(long)jj * CAP + p] = ii;                     \
        }
    DRAIN(0, e0) DRAIN(1, e1) DRAIN(2, e2) DRAIN(3, e3) DRAIN(4, e4)
    DRAIN(5, e5) DRAIN(6, e6) DRAIN(7, e7) DRAIN(8, e8) DRAIN(9, e9)
    #undef DRAIN
}

// ---------------- fused SAGE1 + proj + selfMLP (+step-0 sort; gather v2) ----------------
// Gather restructured per R25's proven mechanism: (node, eg 0..3, fq 0..3)
// threads; each accumulates edges e==eg (mod 4), 4 independent float4 loads
// per edge; shfl_xor(4,8) tree-reduce (eg = lane bits 2-3, wave-local).
// GEMM phases R19-verbatim.
__global__ __launch_bounds__(256)
void sageproj_kernel(const float* __restrict__ h,
                     int* __restrict__ lists, int* __restrict__ cnt,
                     float* __restrict__ degf, int do_sort,
                     const float* __restrict__ Ws1, const float* __restrict__ bl1,
                     const float* __restrict__ Wc2, const float* __restrict__ bl2,
                     const float* __restrict__ Wf1, const float* __restrict__ bf1,
                     const float* __restrict__ Wf2, const float* __restrict__ bf2,
                     float* __restrict__ pl, float* __restrict__ q) {
    __shared__ float v[16][132];     // [node][k]: k<64 aggr, k>=64 h row
    __shared__ float rr[16][132];    // r1
    __shared__ float tt[16][132];    // t = relu(h@Wf1+bf1)
    __shared__ float xsl[16][68];    // xs
    __shared__ float wbuf[64 * 128]; // 32 KB weight panel chunk
    const int tid = threadIdx.x;
    const int nb = blockIdx.x * 16;
    if (do_sort) {                   // canonicalize own 16 nodes (R16/R19-proven)
        const int wv = tid >> 6, lane = tid & 63;
        #pragma unroll 1
        for (int r = 0; r < 4; ++r) {
            const int n = nb + wv * 4 + r;
            int m = cnt[n]; if (m > CAP) m = CAP;
            int val = (lane < m) ? lists[(long)n * CAP + lane] : 0x7FFFFFFF;
            #pragma unroll
            for (int k = 2; k <= 64; k <<= 1) {
                #pragma unroll
                for (int j = k >> 1; j > 0; j >>= 1) {
                    int other = __shfl_xor(val, j);
                    bool keepMin = (((lane & j) == 0) == ((lane & k) == 0));
                    int mn = val < other ? val : other;
                    int mx = val < other ? other : val;
                    val = keepMin ? mn : mx;
                }
            }
            lists[(long)n * CAP + lane] = val;
            if (lane == 0) { cnt[n] = m; degf[n] = (float)(m > 0 ? m : 1); }
        }
        __syncthreads();
    }
    {   // gather v2: 16 threads/node as (eg 0..3) x (fq 0..3)
        const int ln2 = tid >> 4;
        const int eg  = (tid >> 2) & 3;
        const int fq  = tid & 3;
        const int n2 = nb + ln2;
        const int m = cnt[n2];
        const int* l = lists + (long)n2 * CAP;
        float4 a0 = {0,0,0,0}, a1 = {0,0,0,0}, a2 = {0,0,0,0}, a3 = {0,0,0,0};
        for (int e = eg; e < m; e += 4) {
            const float* p = h + (long)l[e] * FEAT + fq * 16;
            float4 b0 = *reinterpret_cast<const float4*>(p);
            float4 b1 = *reinterpret_cast<const float4*>(p + 4);
            float4 b2 = *reinterpret_cast<const float4*>(p + 8);
            float4 b3 = *reinterpret_cast<const float4*>(p + 12);
            a0.x += b0.x; a0.y += b0.y; a0.z += b0.z; a0.w += b0.w;
            a1.x += b1.x; a1.y += b1.y; a1.z += b1.z; a1.w += b1.w;
            a2.x += b2.x; a2.y += b2.y; a2.z += b2.z; a2.w += b2.w;
            a3.x += b3.x; a3.y += b3.y; a3.z += b3.z; a3.w += b3.w;
        }
        #define RED(A)                                                       \
            (A).x += __shfl_xor((A).x, 4); (A).y += __shfl_xor((A).y, 4);    \
            (A).z += __shfl_xor((A).z, 4); (A).w += __shfl_xor((A).w, 4);    \
            (A).x += __shfl_xor((A).x, 8); (A).y += __shfl_xor((A).y, 8);    \
            (A).z += __shfl_xor((A).z, 8); (A).w += __shfl_xor((A).w, 8);
        RED(a0) RED(a1) RED(a2) RED(a3)
        #undef RED
        const float inv = 1.0f / degf[n2];
        float4 sel = (eg == 0) ? a0 : (eg == 1) ? a1 : (eg == 2) ? a2 : a3;
        float4 av = {sel.x * inv, sel.y * inv, sel.z * inv, sel.w * inv};
        *reinterpret_cast<float4*>(&v[ln2][(fq * 4 + eg) * 4]) = av;
        *reinterpret_cast<float4*>(&v[ln2][64 + (eg * 4 + fq) * 4]) =
            *reinterpret_cast<const float4*>(h + (long)n2 * FEAT + (eg * 4 + fq) * 4);
    }
    const int ln = tid >> 4, jg = tid & 15;
    const int n = nb + ln;
    const int c0 = jg * 4;
    // ---- P1: rr = relu([aggr|h] @ Ws1 + bl1), K=128 in 2 chunks ----
    {
        float4 b0 = *reinterpret_cast<const float4*>(bl1 + c0);
        float4 b1 = *reinterpret_cast<const float4*>(bl1 + 64 + c0);
        float A0[4] = {b0.x, b0.y, b0.z, b0.w};
        float A1[4] = {b1.x, b1.y, b1.z, b1.w};
        for (int kc = 0; kc < 2; ++kc) {
            __syncthreads();                     // prev consumers done / v ready
            for (int e = tid; e < 2048; e += 256)
                *(reinterpret_cast<float4*>(wbuf) + e) =
                    *(reinterpret_cast<const float4*>(Ws1 + kc * 8192) + e);
            __syncthreads();
            #pragma unroll 4
            for (int k = 0; k < 64; ++k) {
                float a = v[ln][kc * 64 + k];
                float4 w0 = *reinterpret_cast<const float4*>(&wbuf[k * 128 + c0]);
                float4 w1 = *reinterpret_cast<const float4*>(&wbuf[k * 128 + 64 + c0]);
                A0[0] += a * w0.x; A0[1] += a * w0.y; A0[2] += a * w0.z; A0[3] += a * w0.w;
                A1[0] += a * w1.x; A1[1] += a * w1.y; A1[2] += a * w1.z; A1[3] += a * w1.w;
            }
        }
        float4 o0 = {fmaxf(A0[0],0.f), fmaxf(A0[1],0.f), fmaxf(A0[2],0.f), fmaxf(A0[3],0.f)};
        float4 o1 = {fmaxf(A1[0],0.f), fmaxf(A1[1],0.f), fmaxf(A1[2],0.f), fmaxf(A1[3],0.f)};
        *reinterpret_cast<float4*>(&rr[ln][c0]) = o0;
        *reinterpret_cast<float4*>(&rr[ln][64 + c0]) = o1;
    }
    // ---- P2: tt = relu(h @ Wf1 + bf1), K=64, one chunk ----
    {
        float4 b0 = *reinterpret_cast<const float4*>(bf1 + c0);
        float4 b1 = *reinterpret_cast<const float4*>(bf1 + 64 + c0);
        float A0[4] = {b0.x, b0.y, b0.z, b0.w};
        float A1[4] = {b1.x, b1.y, b1.z, b1.w};
        __syncthreads();
        for (int e = tid; e < 2048; e += 256)
            *(reinterpret_cast<float4*>(wbuf) + e) =
                *(reinterpret_cast<const float4*>(Wf1) + e);
        __syncthreads();
        #pragma unroll 4
        for (int k = 0; k < 64; ++k) {
            float a = v[ln][64 + k];
            float4 w0 = *reinterpret_cast<const float4*>(&wbuf[k * 128 + c0]);
            float4 w1 = *reinterpret_cast<const float4*>(&wbuf[k * 128 + 64 + c0]);
            A0[0] += a * w0.x; A0[1] += a * w0.y; A0[2] += a * w0.z; A0[3] += a * w0.w;
            A1[0] += a * w1.x; A1[1] += a * w1.y; A1[2] += a * w1.z; A1[3] += a * w1.w;
        }
        float4 o0 = {fmaxf(A0[0],0.f), fmaxf(A0[1],0.f), fmaxf(A0[2],0.f), fmaxf(A0[3],0.f)};
        float4 o1 = {fmaxf(A1[0],0.f), fmaxf(A1[1],0.f), fmaxf(A1[2],0.f), fmaxf(A1[3],0.f)};
        *reinterpret_cast<float4*>(&tt[ln][c0]) = o0;
        *reinterpret_cast<float4*>(&tt[ln][64 + c0]) = o1;
    }
    // ---- P3: xsl = tt @ Wf2 + bf2, K=128, 64 cols (Wf2 = [128][64]) ----
    {
        float4 b0 = *reinterpret_cast<const float4*>(bf2 + c0);
        float X[4] = {b0.x, b0.y, b0.z, b0.w};
        __syncthreads();
        for (int e = tid; e < 2048; e += 256)
            *(reinterpret_cast<float4*>(wbuf) + e) =
                *(reinterpret_cast<const float4*>(Wf2) + e);
        __syncthreads();
        #pragma unroll 4
        for (int k = 0; k < 128; ++k) {
            float a = tt[ln][k];
            float4 w = *reinterpret_cast<const float4*>(&wbuf[k * 64 + c0]);
            X[0] += a * w.x; X[1] += a * w.y; X[2] += a * w.z; X[3] += a * w.w;
        }
        float4 o = {X[0], X[1], X[2], X[3]};
        *reinterpret_cast<float4*>(&xsl[ln][c0]) = o;
    }
    // ---- P4: [pl|q] = rr @ Wc2 (+ bl2 + xsl on q half), K=128 in 2 chunks ----
    {
        float P0[4] = {0, 0, 0, 0};
        float P1[4] = {0, 0, 0, 0};
        for (int kc = 0; kc < 2; ++kc) {
            __syncthreads();
            for (int e = tid; e < 2048; e += 256)
                *(reinterpret_cast<float4*>(wbuf) + e) =
                    *(reinterpret_cast<const float4*>(Wc2 + kc * 8192) + e);
            __syncthreads();
            #pragma unroll 4
            for (int k = 0; k < 64; ++k) {
                float a = rr[ln][kc * 64 + k];
                float4 w0 = *reinterpret_cast<const float4*>(&wbuf[k * 128 + c0]);
                float4 w1 = *reinterpret_cast<const float4*>(&wbuf[k * 128 + 64 + c0]);
                P0[0] += a * w0.x; P0[1] += a * w0.y; P0[2] += a * w0.z; P0[3] += a * w0.w;
                P1[0] += a * w1.x; P1[1] += a * w1.y; P1[2] += a * w1.z; P1[3] += a * w1.w;
            }
        }
        float4 op = {P0[0], P0[1], P0[2], P0[3]};
        *reinterpret_cast<float4*>(pl + (long)n * FEAT + c0) = op;
        float4 bv = *reinterpret_cast<const float4*>(bl2 + c0);
        float4 oq = {P1[0] + bv.x + xsl[ln][c0 + 0],
                     P1[1] + bv.y + xsl[ln][c0 + 1],
                     P1[2] + bv.z + xsl[ln][c0 + 2],
                     P1[3] + bv.w + xsl[ln][c0 + 3]};
        *reinterpret_cast<float4*>(q + (long)n * FEAT + c0) = oq;
    }
}

// ---------------- gather + Euler epilogue v3: 16 neighbor-groups x 4 f-threads ----
// Chain depth ~1 (one edge per thread at mean m=16), 4 independent loads/edge;
// shfl_xor(4,8,16,32) tree; writes distributed over eg<4. 2000 blocks.
__global__ __launch_bounds__(256)
void epi_kernel(const float* __restrict__ pl, const float* __restrict__ q,
                const int* __restrict__ lists, const int* __restrict__ cnt,
                const float* __restrict__ degf, const float* __restrict__ hcur,
                const float* __restrict__ tspan, int step,
                float* __restrict__ hnext) {
    const int tid  = threadIdx.x;
    const int nw   = tid >> 6;            // node within block (one wave per node)
    const int lane = tid & 63;
    const int n  = blockIdx.x * 4 + nw;
    const int eg = lane >> 2;             // neighbor group 0..15
    const int fq = lane & 3;              // feature quad 0..3 (4 float4s each)
    const int m  = cnt[n];
    const int* l = lists + (long)n * CAP;
    float4 a0 = {0,0,0,0}, a1 = {0,0,0,0}, a2 = {0,0,0,0}, a3 = {0,0,0,0};
    for (int e = eg; e < m; e += 16) {
        const float* p = pl + (long)l[e] * FEAT + fq * 16;
        float4 b0 = *reinterpret_cast<const float4*>(p);
        float4 b1 = *reinterpret_cast<const float4*>(p + 4);
        float4 b2 = *reinterpret_cast<const float4*>(p + 8);
        float4 b3 = *reinterpret_cast<const float4*>(p + 12);
        a0.x += b0.x; a0.y += b0.y; a0.z += b0.z; a0.w += b0.w;
        a1.x += b1.x; a1.y += b1.y; a1.z += b1.z; a1.w += b1.w;
        a2.x += b2.x; a2.y += b2.y; a2.z += b2.z; a2.w += b2.w;
        a3.x += b3.x; a3.y += b3.y; a3.z += b3.z; a3.w += b3.w;
    }
    #define RED(A)                                                           \
        (A).x += __shfl_xor((A).x, 4);  (A).y += __shfl_xor((A).y, 4);       \
        (A).z += __shfl_xor((A).z, 4);  (A).w += __shfl_xor((A).w, 4);       \
        (A).x += __shfl_xor((A).x, 8);  (A).y += __shfl_xor((A).y, 8);       \
        (A).z += __shfl_xor((A).z, 8);  (A).w += __shfl_xor((A).w, 8);       \
        (A).x += __shfl_xor((A).x, 16); (A).y += __shfl_xor((A).y, 16);      \
        (A).z += __shfl_xor((A).z, 16); (A).w += __shfl_xor((A).w, 16);      \
        (A).x += __shfl_xor((A).x, 32); (A).y += __shfl_xor((A).y, 32);      \
        (A).z += __shfl_xor((A).z, 32); (A).w += __shfl_xor((A).w, 32);
    RED(a0) RED(a1) RED(a2) RED(a3)
    #undef RED
    if (eg < 4) {                         // writer: float4 idx fq*4 + eg
        float4 a = (eg == 0) ? a0 : (eg == 1) ? a1 : (eg == 2) ? a2 : a3;
        const int f0 = (fq * 4 + eg) * 4;
        const float inv = 1.0f / degf[n];
        const float dt = tspan[step + 1] - tspan[step];
        float4 qv = *reinterpret_cast<const float4*>(q + (long)n * FEAT + f0);
        float4 hv = *reinterpret_cast<const float4*>(hcur + (long)n * FEAT + f0);
        float s0 = qv.x + a.x * inv, s1 = qv.y + a.y * inv;
        float s2 = qv.z + a.z * inv, s3 = qv.w + a.w * inv;
        s0 = fminf(fmaxf(s0, -1000.f), 1000.f); s1 = fminf(fmaxf(s1, -1000.f), 1000.f);
        s2 = fminf(fmaxf(s2, -1000.f), 1000.f); s3 = fminf(fmaxf(s3, -1000.f), 1000.f);
        float4 o = {hv.x + dt * s0, hv.y + dt * s1, hv.z + dt * s2, hv.w + dt * s3};
        *reinterpret_cast<float4*>(hnext + (long)n * FEAT + f0) = o;
    }
}

extern "C" void kernel_launch(void* const* d_in, const int* in_sizes, int n_in,
                              void* d_out, int out_size, void* d_ws, size_t ws_size,
                              hipStream_t stream) {
    const float* tspan = (const float*)d_in[0];
    const float* x     = (const float*)d_in[1];
    const float* adj   = (const float*)d_in[2];
    const float* We1   = (const float*)d_in[3];
    const float* be1   = (const float*)d_in[4];
    const float* We2   = (const float*)d_in[5];
    const float* be2   = (const float*)d_in[6];
    const float* Wf1   = (const float*)d_in[7];
    const float* bf1   = (const float*)d_in[8];
    const float* Wf2   = (const float*)d_in[9];
    const float* bf2   = (const float*)d_in[10];
    const float* Wl1   = (const float*)d_in[11];
    const float* bl1   = (const float*)d_in[12];
    const float* Wr1   = (const float*)d_in[13];
    const float* Wl2   = (const float*)d_in[14];
    const float* bl2   = (const float*)d_in[15];
    const float* Wr2   = (const float*)d_in[16];
    float* out = (float*)d_out;

    // workspace layout (bytes)
    char* ws = (char*)d_ws;
    int*   lists = (int*)  (ws + 0);           // 8000*64*4  = 2,048,000
    int*   cnt   = (int*)  (ws + 2048000);     // 32,000
    float* degf  = (float*)(ws + 2080000);     // 32,000
    float* Ws1   = (float*)(ws + 2112000);     // 65,536
    float* Wc2   = (float*)(ws + 2177536);     // 65,536
    float* pl    = (float*)(ws + 2243072);     // 2,048,000
    float* q     = (float*)(ws + 4291072);     // 2,048,000
    // total 6,339,072 bytes

    front_kernel<<<500, 256, 0, stream>>>(cnt, x, We1, be1, We2, be2, out,
                                          Wl1, Wr1, Wl2, Wr2, Ws1, Wc2);
    build_adj_kernel<<<2048, 256, 0, stream>>>(adj, cnt, lists);

    for (int s = 0; s < 3; ++s) {
        const float* hcur  = out + (long)s       * N_NODES * FEAT;
        float*       hnext = out + (long)(s + 1) * N_NODES * FEAT;
        sageproj_kernel<<<500, 256, 0, stream>>>(hcur, lists, cnt, degf, (s == 0) ? 1 : 0,
                                                 Ws1, bl1, Wc2, bl2,
                                                 Wf1, bf1, Wf2, bf2, pl, q);
        epi_kernel<<<2000, 256, 0, stream>>>(pl, q, lists, cnt, degf, hcur, tspan, s, hnext);
    }
}